// Round 10
// baseline (798.375 us; speedup 1.0000x reference)
//
#include <hip/hip_runtime.h>

#define NN 50000
#define NE 200000
#define NG 512
#define NB 6250      // node buckets (8 nodes each)
#define FN 64
#define FE 16
#define FE2 32
#define H 32
#define NL 3
#define EPSV 1e-5f

// ================= mega prep (sections) =================
// sec 0 (96 blocks):  V2[(l*32+i)*512 + f*32+o] = sum_c We[f,c]*Wnn[l][c][i][o]
//                     M[l*1024 + i*32+o] = Bnn[l][i][o] + sum_c be[c]*Wnn[l][c][i][o]
// sec 1 (782 blocks): node embedding h = x@W_node + b_node (+ agg zero)
// sec 2 (782 blocks): bucket degrees + graph counts
__global__ void k_prep(const float* __restrict__ Wnn, const float* __restrict__ We,
                       const float* __restrict__ be, const float* __restrict__ Bnn,
                       float* __restrict__ V2, float* __restrict__ M,
                       const int* __restrict__ src, const int* __restrict__ batch,
                       int* __restrict__ degB, float* __restrict__ cnt,
                       const float* __restrict__ x, const float* __restrict__ Wn,
                       const float* __restrict__ bno, float* __restrict__ h,
                       float* __restrict__ agg) {
    __shared__ float smem[2048];
    int t = threadIdx.x;
    int b = blockIdx.x;
    if (b < 96) {                        // ---- V/M precompute: one block per (l,i)
        int l = b >> 5, i = b & 31;
        float* sWnn = smem;              // [32][32]
        float* sWe  = smem + 1024;       // [16][32]
        for (int j = t; j < 1024; j += 256)
            sWnn[j] = Wnn[((size_t)(l * 32 + (j >> 5))) * 1024 + i * 32 + (j & 31)];
        for (int j = t; j < 512; j += 256) sWe[j] = We[j];
        __syncthreads();
#pragma unroll
        for (int cc = 0; cc < 2; cc++) {
            int c = 2 * t + cc;
            int f = c >> 5, o = c & 31;
            float v = 0.f;
#pragma unroll
            for (int k = 0; k < 32; k++) v += sWe[f * 32 + k] * sWnn[k * 32 + o];
            V2[(size_t)(l * 32 + i) * 512 + c] = v;
        }
        if (t < 32) {
            float m = Bnn[(size_t)l * 1024 + i * 32 + t];
            for (int k = 0; k < 32; k++) m += be[k] * sWnn[k * 32 + t];
            M[l * 1024 + i * 32 + t] = m;
        }
    } else if (b < 878) {                // ---- node embedding: 64 nodes/block
        for (int j = t; j < FN * H; j += 256) smem[j] = Wn[j];
        __syncthreads();
        int n0 = (b - 96) * 64;
        int node8 = t >> 5, o = t & 31;
        for (int r = 0; r < 8; r++) {
            int n = n0 + r * 8 + node8;
            if (n < NN) {
                const float* xr = x + (size_t)n * FN;
                float acc = bno[o];
#pragma unroll 16
                for (int i = 0; i < FN; i++) acc += xr[i] * smem[i * H + o];
                size_t idx = (size_t)n * H + o;
                h[idx] = acc;
                agg[idx] = 0.f;
            }
        }
    } else {                             // ---- bucket degrees + graph counts
        int e = (b - 878) * 256 + t;
        if (e < NE) atomicAdd(&degB[src[e] >> 3], 1);
        if (e < NN) atomicAdd(&cnt[batch[e]], 1.f);
    }
}

// ================= bucket scan (single block): rowptrB/cursorB =================
__global__ void k_scanB(const int* __restrict__ degB, int* __restrict__ rowptrB,
                        int* __restrict__ cursorB) {
    __shared__ int ssum[1024];
    int t = threadIdx.x;
    int loc[7];
    int base = t * 7;
    int s = 0;
#pragma unroll
    for (int i = 0; i < 7; i++) {
        int idx = base + i;
        loc[i] = (idx < NB) ? degB[idx] : 0;
        s += loc[i];
    }
    ssum[t] = s;
    for (int off = 1; off < 1024; off <<= 1) {
        __syncthreads();
        int tv = (t >= off) ? ssum[t - off] : 0;
        __syncthreads();
        ssum[t] += tv;
    }
    __syncthreads();
    int run = ssum[t] - s;
#pragma unroll
    for (int i = 0; i < 7; i++) {
        int idx = base + i;
        if (idx < NB) { rowptrB[idx] = run; cursorB[idx] = run; run += loc[i]; }
    }
    if (t == 1023) rowptrB[NB] = ssum[1023];
}

__global__ void k_fill(const int* __restrict__ src, int* __restrict__ cursorB,
                       int* __restrict__ eid) {
    int e = blockIdx.x * 256 + threadIdx.x;
    if (e >= NE) return;
    int p = atomicAdd(&cursorB[src[e] >> 3], 1);
    eid[p] = e;
}

// ================= fused NNConv v7 (rank-16 folded) =================
// 256 threads, 8 nodes/block, ~17 KB LDS -> 8 blocks/CU.
// Pre: h (from h0 or BN(z_prev)), z = h@Wr+bc -> global, su = h@M -> LDS.
// Phase A (barrier-free): U[8][512] = h @ V (thread owns 2 cols, streams V rows
// from L2 as coalesced float2). Phase B: 4 waves x 2 edges, raw eattr (16 floats)
// staged in private double-buffered sea; 16 conflict-free b32 U reads/edge;
// 1 atomicAdd/lane.
__global__ __launch_bounds__(256, 8) void k_conv(
    const float* __restrict__ h0, const float* __restrict__ eattr,
    const float* __restrict__ V2l, const float* __restrict__ Ml,
    const int* __restrict__ rowptrB, const int* __restrict__ eid,
    const int* __restrict__ src, const int* __restrict__ dst,
    float* __restrict__ agg, float* __restrict__ z,
    const float* __restrict__ statsPrev, float* __restrict__ statsZero,
    const float* __restrict__ gm, const float* __restrict__ bt,
    const float* __restrict__ Wr, const float* __restrict__ bc, int first) {
    __shared__ __align__(16) float sU[8][512];    // 16 KB U tile
    __shared__ __align__(16) float shh[8][32];
    __shared__ __align__(16) float su[8][32];
    __shared__ __align__(16) float sea[4][2][32]; // per-wave double-buffered eattr
    int t = threadIdx.x;
    int nb0 = blockIdx.x * 8;
    if (blockIdx.x == 0 && t < 64) statsZero[t] = 0.f;

    // ---- pre: h / z / u for the block's 8 nodes
    {
        int node = t >> 5, o = t & 31;
        size_t idx = (size_t)(nb0 + node) * H + o;
        float hv;
        if (first) {
            hv = h0[idx];
        } else {
            const float invn = 1.0f / (float)NN;
            float mu = statsPrev[o] * invn;
            float var = statsPrev[32 + o] * invn - mu * mu;
            float v = (z[idx] - mu) * rsqrtf(var + EPSV) * gm[o] + bt[o];
            hv = v > 0.f ? v : 0.f;
        }
        shh[node][o] = hv;
        __builtin_amdgcn_wave_barrier();   // shh row (same wave) before reads
        float a = bc[o], bacc = 0.f;
#pragma unroll
        for (int i = 0; i < H; i++) {
            float hh = shh[node][i];
            a += hh * Wr[i * H + o];
            bacc += hh * Ml[i * H + o];
        }
        z[idx] = a;
        su[node][o] = bacc;
    }
    __syncthreads();

    // ---- Phase A: U[8][512] in LDS (no barriers inside)
    {
        const float* vp = V2l + 2 * t;       // this thread's 2 cols
        float2 acc[8];
#pragma unroll
        for (int n = 0; n < 8; n++) acc[n] = make_float2(0.f, 0.f);
#pragma unroll
        for (int i4 = 0; i4 < 8; i4++) {
            float2 v0 = *(const float2*)(vp + (size_t)(i4 * 4 + 0) * 512);
            float2 v1 = *(const float2*)(vp + (size_t)(i4 * 4 + 1) * 512);
            float2 v2 = *(const float2*)(vp + (size_t)(i4 * 4 + 2) * 512);
            float2 v3 = *(const float2*)(vp + (size_t)(i4 * 4 + 3) * 512);
#pragma unroll
            for (int n = 0; n < 8; n++) {
                float4 hv = *(const float4*)&shh[n][i4 * 4];
                acc[n].x += hv.x * v0.x + hv.y * v1.x + hv.z * v2.x + hv.w * v3.x;
                acc[n].y += hv.x * v0.y + hv.y * v1.y + hv.z * v2.y + hv.w * v3.y;
            }
        }
#pragma unroll
        for (int n = 0; n < 8; n++)
            *(float2*)&sU[n][2 * t] = acc[n];
    }
    __syncthreads();   // U tile complete

    // ---- Phase B (no block barriers)
    int E0 = rowptrB[blockIdx.x], E1 = rowptrB[blockIdx.x + 1];
    int w = t >> 6;
    int lane = t & 63;
    int hw = lane >> 5;
    int o = lane & 31;
    int buf = 0;
    for (int jb = E0 + 2 * w; jb < E1; jb += 8, buf ^= 1) {
        int j = jb + hw;
        bool act = (j < E1);
        int sn = 0, d = 0;
        if (act) {
            int e = eid[j];
            sn = src[e] - nb0;
            d = dst[e];
            if (o < 16) sea[w][buf][hw * 16 + o] = eattr[(size_t)e * FE + o];
        }
        __builtin_amdgcn_wave_barrier();   // LDS write before reads (same wave)
        if (act) {
            const float* sef = &sea[w][buf][hw * 16];
            float m = su[sn][o];
            const float* tp = &sU[sn][0];
#pragma unroll
            for (int f4 = 0; f4 < 4; f4++) {
                float4 se = *(const float4*)&sef[f4 * 4];
                m += se.x * tp[(f4 * 4 + 0) * 32 + o];
                m += se.y * tp[(f4 * 4 + 1) * 32 + o];
                m += se.z * tp[(f4 * 4 + 2) * 32 + o];
                m += se.w * tp[(f4 * 4 + 3) * 32 + o];
            }
            atomicAdd(&agg[(size_t)d * H + o], m);
        }
        __builtin_amdgcn_wave_barrier();
    }
}

// ================= z += agg (agg re-zeroed); per-channel sum & sumsq =================
__global__ void k_add_stats(float* __restrict__ z, float* __restrict__ agg,
                            float* __restrict__ stats) {
    __shared__ float red[256];
    int t = threadIdx.x;
    float s = 0.f, s2 = 0.f;
    for (size_t idx = (size_t)blockIdx.x * 256 + t; idx < (size_t)NN * H;
         idx += (size_t)gridDim.x * 256) {
        float v = z[idx] + agg[idx];
        z[idx] = v;
        agg[idx] = 0.f;
        s += v;
        s2 += v * v;
    }
    red[t] = s;
    __syncthreads();
    for (int st = 128; st >= 32; st >>= 1) {
        if (t < st) red[t] += red[t + st];
        __syncthreads();
    }
    if (t < 32) atomicAdd(&stats[t], red[t]);
    __syncthreads();
    red[t] = s2;
    __syncthreads();
    for (int st = 128; st >= 32; st >>= 1) {
        if (t < st) red[t] += red[t + st];
        __syncthreads();
    }
    if (t < 32) atomicAdd(&stats[32 + t], red[t]);
}

// ================= fused BN+ReLU -> graph pool (last layer) =================
__global__ void k_bn_pool(const float* __restrict__ z, const float* __restrict__ stats,
                          const float* __restrict__ gm, const float* __restrict__ bt,
                          const int* __restrict__ batch, float* __restrict__ gsum) {
    int idx = blockIdx.x * 256 + threadIdx.x;
    if (idx >= NN * H) return;
    int n = idx >> 5, o = idx & 31;
    const float invn = 1.0f / (float)NN;
    float mu = stats[o] * invn;
    float var = stats[32 + o] * invn - mu * mu;
    float v = (z[idx] - mu) * rsqrtf(var + EPSV) * gm[o] + bt[o];
    v = v > 0.f ? v : 0.f;
    atomicAdd(&gsum[(size_t)batch[n] * H + o], v);
}

// ================= head =================
__global__ void k_head(const float* __restrict__ gsum, const float* __restrict__ cnt,
                       const float* __restrict__ W2, const float* __restrict__ b2,
                       const float* __restrict__ W3, const float* __restrict__ b3,
                       float* __restrict__ out) {
    __shared__ float sW2[H * 16];
    __shared__ float sW3[16];
    __shared__ float sb2[16];
    int t = threadIdx.x;
    for (int j = t; j < H * 16; j += 256) sW2[j] = W2[j];
    if (t < 16) { sW3[t] = W3[t]; sb2[t] = b2[t]; }
    __syncthreads();
    int g = blockIdx.x * 256 + t;
    if (g >= NG) return;
    float inv = 1.0f / fmaxf(cnt[g], 1.0f);
    float gx[H];
#pragma unroll
    for (int i = 0; i < H; i++) gx[i] = gsum[g * H + i] * inv;
    float o3 = b3[0];
#pragma unroll
    for (int j = 0; j < 16; j++) {
        float hh = sb2[j];
#pragma unroll
        for (int i = 0; i < H; i++) hh += gx[i] * sW2[i * 16 + j];
        hh = hh > 0.f ? hh : 0.f;
        o3 += hh * sW3[j];
    }
    out[g] = o3;
}

extern "C" void kernel_launch(void* const* d_in, const int* in_sizes, int n_in,
                              void* d_out, int out_size, void* d_ws, size_t ws_size,
                              hipStream_t stream) {
    const float* x      = (const float*)d_in[0];
    const float* eattr  = (const float*)d_in[1];
    const float* W_node = (const float*)d_in[2];
    const float* b_node = (const float*)d_in[3];
    const float* W_edge = (const float*)d_in[4];
    const float* b_edge = (const float*)d_in[5];
    const float* W_nn   = (const float*)d_in[6];
    const float* b_nn   = (const float*)d_in[7];
    const float* W_root = (const float*)d_in[8];
    const float* b_conv = (const float*)d_in[9];
    const float* gamma  = (const float*)d_in[10];
    const float* beta   = (const float*)d_in[11];
    const float* W2     = (const float*)d_in[12];
    const float* b2     = (const float*)d_in[13];
    const float* W3     = (const float*)d_in[14];
    const float* b3     = (const float*)d_in[15];
    const int* eidx     = (const int*)d_in[16];
    const int* batch    = (const int*)d_in[17];
    const int* src = eidx;
    const int* dst = eidx + NE;
    float* out = (float*)d_out;

    const size_t NNH = (size_t)NN * H;
    float* ws = (float*)d_ws;
    float* h      = ws;                        // NN*32 (h0 only)
    float* z      = h + NNH;                   // NN*32
    float* agg    = z + NNH;                   // NN*32
    float* stats  = agg + NNH;                 // 2*64 ping-pong
    float* V2     = stats + 128;               // 3*32*512
    float* M      = V2 + (size_t)NL * 32 * 512;// 3*1024
    int*   degB   = (int*)(M + NL * 1024);     // NB
    float* gsum   = (float*)(degB + NB);       // NG*32 (contig with degB,cnt: one memset)
    float* cnt    = gsum + (size_t)NG * H;     // NG
    int*   rowptrB = (int*)(cnt + NG);         // NB+1
    int*   cursorB = rowptrB + NB + 1;         // NB
    int*   eid    = cursorB + NB;              // NE

    // zero degB | gsum | cnt in one shot
    hipMemsetAsync(degB, 0, (NB + NG * H + NG) * sizeof(int), stream);

    // mega prep: V/M (96) | node emb (782) | degB/cnt (782)
    k_prep<<<96 + 782 + 782, 256, 0, stream>>>(
        W_nn, W_edge, b_edge, b_nn, V2, M, src, batch, degB, cnt,
        x, W_node, b_node, h, agg);
    k_scanB<<<1, 1024, 0, stream>>>(degB, rowptrB, cursorB);
    k_fill<<<(NE + 255) / 256, 256, 0, stream>>>(src, cursorB, eid);

    for (int l = 0; l < NL; l++) {
        float* statsCur  = stats + (l & 1) * 64;
        float* statsPrev = stats + ((l + 1) & 1) * 64;
        int lp = (l > 0) ? (l - 1) : 0;
        k_conv<<<NB, 256, 0, stream>>>(h, eattr, V2 + (size_t)l * 32 * 512,
                                       M + (size_t)l * 1024,
                                       rowptrB, eid, src, dst, agg, z,
                                       statsPrev, statsCur,
                                       gamma + lp * H, beta + lp * H,
                                       W_root + (size_t)l * H * H, b_conv + l * H,
                                       l == 0 ? 1 : 0);
        k_add_stats<<<512, 256, 0, stream>>>(z, agg, statsCur);
    }

    k_bn_pool<<<NB, 256, 0, stream>>>(z, stats + ((NL - 1) & 1) * 64,
                                      gamma + (NL - 1) * H, beta + (NL - 1) * H,
                                      batch, gsum);
    k_head<<<2, 256, 0, stream>>>(gsum, cnt, W2, b2, W3, b3, out);
}

// Round 11
// 357.123 us; speedup vs baseline: 2.2356x; 2.2356x over previous
//
#include <hip/hip_runtime.h>

#define NN 50000
#define NE 200000
#define NG 512
#define NB 6250      // node buckets (8 nodes each)
#define FN 64
#define FE 16
#define FE2 32
#define H 32
#define NL 3
#define EPSV 1e-5f

// ================= mega prep (sections) =================
// sec 0 (96 blocks):  V2[(l*32+i)*512 + f*32+o] = sum_c We[f,c]*Wnn[l][c][i][o]
//                     M[l*1024 + i*32+o] = Bnn[l][i][o] + sum_c be[c]*Wnn[l][c][i][o]
// sec 1 (782 blocks): node embedding h = x@W_node + b_node (+ agg zero)
// sec 2 (782 blocks): bucket degrees + graph counts
__global__ void k_prep(const float* __restrict__ Wnn, const float* __restrict__ We,
                       const float* __restrict__ be, const float* __restrict__ Bnn,
                       float* __restrict__ V2, float* __restrict__ M,
                       const int* __restrict__ src, const int* __restrict__ batch,
                       int* __restrict__ degB, float* __restrict__ cnt,
                       const float* __restrict__ x, const float* __restrict__ Wn,
                       const float* __restrict__ bno, float* __restrict__ h,
                       float* __restrict__ agg) {
    __shared__ float smem[2048];
    int t = threadIdx.x;
    int b = blockIdx.x;
    if (b < 96) {                        // ---- V/M precompute: one block per (l,i)
        int l = b >> 5, i = b & 31;
        float* sWnn = smem;              // [32][32]
        float* sWe  = smem + 1024;       // [16][32]
        for (int j = t; j < 1024; j += 256)
            sWnn[j] = Wnn[((size_t)(l * 32 + (j >> 5))) * 1024 + i * 32 + (j & 31)];
        for (int j = t; j < 512; j += 256) sWe[j] = We[j];
        __syncthreads();
#pragma unroll
        for (int cc = 0; cc < 2; cc++) {
            int c = 2 * t + cc;
            int f = c >> 5, o = c & 31;
            float v = 0.f;
#pragma unroll
            for (int k = 0; k < 32; k++) v += sWe[f * 32 + k] * sWnn[k * 32 + o];
            V2[(size_t)(l * 32 + i) * 512 + c] = v;
        }
        if (t < 32) {
            float m = Bnn[(size_t)l * 1024 + i * 32 + t];
            for (int k = 0; k < 32; k++) m += be[k] * sWnn[k * 32 + t];
            M[l * 1024 + i * 32 + t] = m;
        }
    } else if (b < 878) {                // ---- node embedding: 64 nodes/block
        for (int j = t; j < FN * H; j += 256) smem[j] = Wn[j];
        __syncthreads();
        int n0 = (b - 96) * 64;
        int node8 = t >> 5, o = t & 31;
        for (int r = 0; r < 8; r++) {
            int n = n0 + r * 8 + node8;
            if (n < NN) {
                const float* xr = x + (size_t)n * FN;
                float acc = bno[o];
#pragma unroll 16
                for (int i = 0; i < FN; i++) acc += xr[i] * smem[i * H + o];
                size_t idx = (size_t)n * H + o;
                h[idx] = acc;
                agg[idx] = 0.f;
            }
        }
    } else {                             // ---- bucket degrees + graph counts
        int e = (b - 878) * 256 + t;
        if (e < NE) atomicAdd(&degB[src[e] >> 3], 1);
        if (e < NN) atomicAdd(&cnt[batch[e]], 1.f);
    }
}

// ================= bucket scan (single block): rowptrB/cursorB =================
__global__ void k_scanB(const int* __restrict__ degB, int* __restrict__ rowptrB,
                        int* __restrict__ cursorB) {
    __shared__ int ssum[1024];
    int t = threadIdx.x;
    int loc[7];
    int base = t * 7;
    int s = 0;
#pragma unroll
    for (int i = 0; i < 7; i++) {
        int idx = base + i;
        loc[i] = (idx < NB) ? degB[idx] : 0;
        s += loc[i];
    }
    ssum[t] = s;
    for (int off = 1; off < 1024; off <<= 1) {
        __syncthreads();
        int tv = (t >= off) ? ssum[t - off] : 0;
        __syncthreads();
        ssum[t] += tv;
    }
    __syncthreads();
    int run = ssum[t] - s;
#pragma unroll
    for (int i = 0; i < 7; i++) {
        int idx = base + i;
        if (idx < NB) { rowptrB[idx] = run; cursorB[idx] = run; run += loc[i]; }
    }
    if (t == 1023) rowptrB[NB] = ssum[1023];
}

__global__ void k_fill(const int* __restrict__ src, int* __restrict__ cursorB,
                       int* __restrict__ eid) {
    int e = blockIdx.x * 256 + threadIdx.x;
    if (e >= NE) return;
    int p = atomicAdd(&cursorB[src[e] >> 3], 1);
    eid[p] = e;
}

// ================= fused NNConv v7b (rank-16 folded, sane register cap) =================
// 256 threads, 8 nodes/block, ~17 KB LDS.
// Pre: h (from h0 or BN(z_prev)), z = h@Wr+bc -> global, su = h@M -> LDS.
// Phase A (barrier-free): U[8][512] = h @ V (thread owns 2 cols, streams V rows
// from L2 as coalesced float2). Phase B: 4 waves x 2 edges, raw eattr (16 floats)
// staged in private double-buffered sea; 16 conflict-free b32 U reads/edge;
// 1 atomicAdd/lane.
__global__ __launch_bounds__(256, 4) void k_conv(
    const float* __restrict__ h0, const float* __restrict__ eattr,
    const float* __restrict__ V2l, const float* __restrict__ Ml,
    const int* __restrict__ rowptrB, const int* __restrict__ eid,
    const int* __restrict__ src, const int* __restrict__ dst,
    float* __restrict__ agg, float* __restrict__ z,
    const float* __restrict__ statsPrev, float* __restrict__ statsZero,
    const float* __restrict__ gm, const float* __restrict__ bt,
    const float* __restrict__ Wr, const float* __restrict__ bc, int first) {
    __shared__ __align__(16) float sU[8][512];    // 16 KB U tile
    __shared__ __align__(16) float shh[8][32];
    __shared__ __align__(16) float su[8][32];
    __shared__ __align__(16) float sea[4][2][32]; // per-wave double-buffered eattr
    int t = threadIdx.x;
    int nb0 = blockIdx.x * 8;
    if (blockIdx.x == 0 && t < 64) statsZero[t] = 0.f;

    // ---- pre: h / z / u for the block's 8 nodes
    {
        int node = t >> 5, o = t & 31;
        size_t idx = (size_t)(nb0 + node) * H + o;
        float hv;
        if (first) {
            hv = h0[idx];
        } else {
            const float invn = 1.0f / (float)NN;
            float mu = statsPrev[o] * invn;
            float var = statsPrev[32 + o] * invn - mu * mu;
            float v = (z[idx] - mu) * rsqrtf(var + EPSV) * gm[o] + bt[o];
            hv = v > 0.f ? v : 0.f;
        }
        shh[node][o] = hv;
        __builtin_amdgcn_wave_barrier();   // shh row (same wave) before reads
        float a = bc[o], bacc = 0.f;
#pragma unroll
        for (int i = 0; i < H; i++) {
            float hh = shh[node][i];
            a += hh * Wr[i * H + o];
            bacc += hh * Ml[i * H + o];
        }
        z[idx] = a;
        su[node][o] = bacc;
    }
    __syncthreads();

    // ---- Phase A: U[8][512] in LDS (no barriers inside)
    {
        const float* vp = V2l + 2 * t;       // this thread's 2 cols
        float2 acc[8];
#pragma unroll
        for (int n = 0; n < 8; n++) acc[n] = make_float2(0.f, 0.f);
#pragma unroll
        for (int i4 = 0; i4 < 8; i4++) {
            float2 v0 = *(const float2*)(vp + (size_t)(i4 * 4 + 0) * 512);
            float2 v1 = *(const float2*)(vp + (size_t)(i4 * 4 + 1) * 512);
            float2 v2 = *(const float2*)(vp + (size_t)(i4 * 4 + 2) * 512);
            float2 v3 = *(const float2*)(vp + (size_t)(i4 * 4 + 3) * 512);
#pragma unroll
            for (int n = 0; n < 8; n++) {
                float4 hv = *(const float4*)&shh[n][i4 * 4];
                acc[n].x += hv.x * v0.x + hv.y * v1.x + hv.z * v2.x + hv.w * v3.x;
                acc[n].y += hv.x * v0.y + hv.y * v1.y + hv.z * v2.y + hv.w * v3.y;
            }
        }
#pragma unroll
        for (int n = 0; n < 8; n++)
            *(float2*)&sU[n][2 * t] = acc[n];
    }
    __syncthreads();   // U tile complete

    // ---- Phase B (no block barriers)
    int E0 = rowptrB[blockIdx.x], E1 = rowptrB[blockIdx.x + 1];
    int w = t >> 6;
    int lane = t & 63;
    int hw = lane >> 5;
    int o = lane & 31;
    int buf = 0;
    for (int jb = E0 + 2 * w; jb < E1; jb += 8, buf ^= 1) {
        int j = jb + hw;
        bool act = (j < E1);
        int sn = 0, d = 0;
        if (act) {
            int e = eid[j];
            sn = src[e] - nb0;
            d = dst[e];
            if (o < 16) sea[w][buf][hw * 16 + o] = eattr[(size_t)e * FE + o];
        }
        __builtin_amdgcn_wave_barrier();   // LDS write before reads (same wave)
        if (act) {
            const float* sef = &sea[w][buf][hw * 16];
            float m = su[sn][o];
            const float* tp = &sU[sn][0];
#pragma unroll
            for (int f4 = 0; f4 < 4; f4++) {
                float4 se = *(const float4*)&sef[f4 * 4];
                m += se.x * tp[(f4 * 4 + 0) * 32 + o];
                m += se.y * tp[(f4 * 4 + 1) * 32 + o];
                m += se.z * tp[(f4 * 4 + 2) * 32 + o];
                m += se.w * tp[(f4 * 4 + 3) * 32 + o];
            }
            atomicAdd(&agg[(size_t)d * H + o], m);
        }
        __builtin_amdgcn_wave_barrier();
    }
}

// ================= z += agg (agg re-zeroed); per-channel sum & sumsq =================
__global__ void k_add_stats(float* __restrict__ z, float* __restrict__ agg,
                            float* __restrict__ stats) {
    __shared__ float red[256];
    int t = threadIdx.x;
    float s = 0.f, s2 = 0.f;
    for (size_t idx = (size_t)blockIdx.x * 256 + t; idx < (size_t)NN * H;
         idx += (size_t)gridDim.x * 256) {
        float v = z[idx] + agg[idx];
        z[idx] = v;
        agg[idx] = 0.f;
        s += v;
        s2 += v * v;
    }
    red[t] = s;
    __syncthreads();
    for (int st = 128; st >= 32; st >>= 1) {
        if (t < st) red[t] += red[t + st];
        __syncthreads();
    }
    if (t < 32) atomicAdd(&stats[t], red[t]);
    __syncthreads();
    red[t] = s2;
    __syncthreads();
    for (int st = 128; st >= 32; st >>= 1) {
        if (t < st) red[t] += red[t + st];
        __syncthreads();
    }
    if (t < 32) atomicAdd(&stats[32 + t], red[t]);
}

// ================= fused BN+ReLU -> graph pool (last layer) =================
__global__ void k_bn_pool(const float* __restrict__ z, const float* __restrict__ stats,
                          const float* __restrict__ gm, const float* __restrict__ bt,
                          const int* __restrict__ batch, float* __restrict__ gsum) {
    int idx = blockIdx.x * 256 + threadIdx.x;
    if (idx >= NN * H) return;
    int n = idx >> 5, o = idx & 31;
    const float invn = 1.0f / (float)NN;
    float mu = stats[o] * invn;
    float var = stats[32 + o] * invn - mu * mu;
    float v = (z[idx] - mu) * rsqrtf(var + EPSV) * gm[o] + bt[o];
    v = v > 0.f ? v : 0.f;
    atomicAdd(&gsum[(size_t)batch[n] * H + o], v);
}

// ================= head =================
__global__ void k_head(const float* __restrict__ gsum, const float* __restrict__ cnt,
                       const float* __restrict__ W2, const float* __restrict__ b2,
                       const float* __restrict__ W3, const float* __restrict__ b3,
                       float* __restrict__ out) {
    __shared__ float sW2[H * 16];
    __shared__ float sW3[16];
    __shared__ float sb2[16];
    int t = threadIdx.x;
    for (int j = t; j < H * 16; j += 256) sW2[j] = W2[j];
    if (t < 16) { sW3[t] = W3[t]; sb2[t] = b2[t]; }
    __syncthreads();
    int g = blockIdx.x * 256 + t;
    if (g >= NG) return;
    float inv = 1.0f / fmaxf(cnt[g], 1.0f);
    float gx[H];
#pragma unroll
    for (int i = 0; i < H; i++) gx[i] = gsum[g * H + i] * inv;
    float o3 = b3[0];
#pragma unroll
    for (int j = 0; j < 16; j++) {
        float hh = sb2[j];
#pragma unroll
        for (int i = 0; i < H; i++) hh += gx[i] * sW2[i * 16 + j];
        hh = hh > 0.f ? hh : 0.f;
        o3 += hh * sW3[j];
    }
    out[g] = o3;
}

extern "C" void kernel_launch(void* const* d_in, const int* in_sizes, int n_in,
                              void* d_out, int out_size, void* d_ws, size_t ws_size,
                              hipStream_t stream) {
    const float* x      = (const float*)d_in[0];
    const float* eattr  = (const float*)d_in[1];
    const float* W_node = (const float*)d_in[2];
    const float* b_node = (const float*)d_in[3];
    const float* W_edge = (const float*)d_in[4];
    const float* b_edge = (const float*)d_in[5];
    const float* W_nn   = (const float*)d_in[6];
    const float* b_nn   = (const float*)d_in[7];
    const float* W_root = (const float*)d_in[8];
    const float* b_conv = (const float*)d_in[9];
    const float* gamma  = (const float*)d_in[10];
    const float* beta   = (const float*)d_in[11];
    const float* W2     = (const float*)d_in[12];
    const float* b2     = (const float*)d_in[13];
    const float* W3     = (const float*)d_in[14];
    const float* b3     = (const float*)d_in[15];
    const int* eidx     = (const int*)d_in[16];
    const int* batch    = (const int*)d_in[17];
    const int* src = eidx;
    const int* dst = eidx + NE;
    float* out = (float*)d_out;

    const size_t NNH = (size_t)NN * H;
    float* ws = (float*)d_ws;
    float* h      = ws;                        // NN*32 (h0 only)
    float* z      = h + NNH;                   // NN*32
    float* agg    = z + NNH;                   // NN*32
    float* stats  = agg + NNH;                 // 2*64 ping-pong
    float* V2     = stats + 128;               // 3*32*512
    float* M      = V2 + (size_t)NL * 32 * 512;// 3*1024
    int*   degB   = (int*)(M + NL * 1024);     // NB
    float* gsum   = (float*)(degB + NB);       // NG*32 (contig with degB,cnt: one memset)
    float* cnt    = gsum + (size_t)NG * H;     // NG
    int*   rowptrB = (int*)(cnt + NG);         // NB+1
    int*   cursorB = rowptrB + NB + 1;         // NB
    int*   eid    = cursorB + NB;              // NE

    // zero degB | gsum | cnt in one shot
    hipMemsetAsync(degB, 0, (NB + NG * H + NG) * sizeof(int), stream);

    // mega prep: V/M (96) | node emb (782) | degB/cnt (782)
    k_prep<<<96 + 782 + 782, 256, 0, stream>>>(
        W_nn, W_edge, b_edge, b_nn, V2, M, src, batch, degB, cnt,
        x, W_node, b_node, h, agg);
    k_scanB<<<1, 1024, 0, stream>>>(degB, rowptrB, cursorB);
    k_fill<<<(NE + 255) / 256, 256, 0, stream>>>(src, cursorB, eid);

    for (int l = 0; l < NL; l++) {
        float* statsCur  = stats + (l & 1) * 64;
        float* statsPrev = stats + ((l + 1) & 1) * 64;
        int lp = (l > 0) ? (l - 1) : 0;
        k_conv<<<NB, 256, 0, stream>>>(h, eattr, V2 + (size_t)l * 32 * 512,
                                       M + (size_t)l * 1024,
                                       rowptrB, eid, src, dst, agg, z,
                                       statsPrev, statsCur,
                                       gamma + lp * H, beta + lp * H,
                                       W_root + (size_t)l * H * H, b_conv + l * H,
                                       l == 0 ? 1 : 0);
        k_add_stats<<<512, 256, 0, stream>>>(z, agg, statsCur);
    }

    k_bn_pool<<<NB, 256, 0, stream>>>(z, stats + ((NL - 1) & 1) * 64,
                                      gamma + (NL - 1) * H, beta + (NL - 1) * H,
                                      batch, gsum);
    k_head<<<2, 256, 0, stream>>>(gsum, cnt, W2, b2, W3, b3, out);
}